// Round 1
// 662.191 us; speedup vs baseline: 1.0095x; 1.0095x over previous
//
#include <hip/hip_runtime.h>
#include <math.h>

// Problem constants (match reference).
#define BB 512
#define KK 32
#define DD 768
#define NEG_INF (-1e30f)

// One block per sample b. 1024 threads = 16 waves -> 2 blocks/CU x 16 waves
// = 32 waves/CU (max occupancy), 4x the previous version's 8 waves/CU.
// Wave w handles candidates k0=w and k1=w+16; all 6 weight float4 loads are
// issued up-front (branchless: padded slots read row 0, an L2 hit) so the
// random-row HBM gather latency is hidden by wave parallelism + ILP.
__global__ __launch_bounds__(1024) void cbert_logits_kernel(
    const float* __restrict__ reps,      // [B, D]
    const float* __restrict__ weight,    // [N, D]
    const float* __restrict__ bias,      // [N]
    const int*   __restrict__ sense_ids, // [B, K]
    const int*   __restrict__ target_ids,// [B]
    float* __restrict__ out,             // [1 + B]: loss slot + correct flags
    float* __restrict__ nll_ws)          // [B] scratch
{
    __shared__ float4 s_repv[DD / 4];
    __shared__ float  s_logits[KK];

    const int b   = blockIdx.x;
    const int tid = threadIdx.x;

    // Stage reps row (768 floats = 192 float4) into LDS, coalesced.
    const float4* repv = reinterpret_cast<const float4*>(reps + (size_t)b * DD);
    if (tid < DD / 4) s_repv[tid] = repv[tid];

    const int wave = tid >> 6;
    const int lane = tid & 63;
    const int k0 = wave;
    const int k1 = wave + 16;

    // Wave-uniform candidate ids (scalar loads), issued before the barrier.
    const int id0 = sense_ids[b * KK + k0];
    const int id1 = sense_ids[b * KK + k1];
    const int g0  = (id0 < 0) ? 0 : id0;   // dummy row 0 for padding slots
    const int g1  = (id1 < 0) ? 0 : id1;

    const float4* w0 = reinterpret_cast<const float4*>(weight + (size_t)g0 * DD);
    const float4* w1 = reinterpret_cast<const float4*>(weight + (size_t)g1 * DD);

    // Issue ALL global loads up-front: 6 x dwordx4 per lane in flight.
    const float4 a0 = w0[0 * 64 + lane];
    const float4 a1 = w0[1 * 64 + lane];
    const float4 a2 = w0[2 * 64 + lane];
    const float4 c0 = w1[0 * 64 + lane];
    const float4 c1 = w1[1 * 64 + lane];
    const float4 c2 = w1[2 * 64 + lane];
    const float bias0 = bias[g0];
    const float bias1 = bias[g1];

    __syncthreads();

    const float4 r0 = s_repv[0 * 64 + lane];
    const float4 r1 = s_repv[1 * 64 + lane];
    const float4 r2 = s_repv[2 * 64 + lane];

    // Same accumulation order as the previous (verified) kernel:
    // acc += x + y + z + w, j = 0,1,2.
    float acc0 = 0.0f;
    acc0 += a0.x * r0.x + a0.y * r0.y + a0.z * r0.z + a0.w * r0.w;
    acc0 += a1.x * r1.x + a1.y * r1.y + a1.z * r1.z + a1.w * r1.w;
    acc0 += a2.x * r2.x + a2.y * r2.y + a2.z * r2.z + a2.w * r2.w;
    float acc1 = 0.0f;
    acc1 += c0.x * r0.x + c0.y * r0.y + c0.z * r0.z + c0.w * r0.w;
    acc1 += c1.x * r1.x + c1.y * r1.y + c1.z * r1.z + c1.w * r1.w;
    acc1 += c2.x * r2.x + c2.y * r2.y + c2.z * r2.z + c2.w * r2.w;

    // Two interleaved 64-lane reductions (independent dep chains -> ILP).
    #pragma unroll
    for (int off = 32; off >= 1; off >>= 1) {
        acc0 += __shfl_down(acc0, off, 64);
        acc1 += __shfl_down(acc1, off, 64);
    }

    if (lane == 0) {
        s_logits[k0] = (id0 < 0) ? NEG_INF : acc0 + bias0;
        s_logits[k1] = (id1 < 0) ? NEG_INF : acc1 + bias1;
    }
    __syncthreads();

    if (tid == 0) {
        // max + argmax (first occurrence on ties, matching jnp.argmax).
        float m = s_logits[0];
        int   am = 0;
        for (int k = 1; k < KK; ++k) {
            const float v = s_logits[k];
            if (v > m) { m = v; am = k; }
        }
        float se = 0.0f;
        for (int k = 0; k < KK; ++k) se += expf(s_logits[k] - m);
        const int tgt = target_ids[b];
        const float nll = -(s_logits[tgt] - m - logf(se));
        nll_ws[b]    = nll;
        out[1 + b]   = (am == tgt) ? 1.0f : 0.0f;
    }
}

// Single-wave reduction of the 512 per-sample NLLs -> mean loss.
// (Kept bit-identical to the verified version.)
__global__ __launch_bounds__(64) void cbert_loss_kernel(
    const float* __restrict__ nll_ws, float* __restrict__ out)
{
    const int lane = threadIdx.x;
    float acc = 0.0f;
    for (int i = lane; i < BB; i += 64) acc += nll_ws[i];
    #pragma unroll
    for (int off = 32; off >= 1; off >>= 1)
        acc += __shfl_down(acc, off, 64);
    if (lane == 0) out[0] = acc / (float)BB;
}

extern "C" void kernel_launch(void* const* d_in, const int* in_sizes, int n_in,
                              void* d_out, int out_size, void* d_ws, size_t ws_size,
                              hipStream_t stream) {
    const float* reps       = (const float*)d_in[0];
    const float* weight     = (const float*)d_in[1];
    const float* bias       = (const float*)d_in[2];
    const int*   sense_ids  = (const int*)d_in[3];
    const int*   target_ids = (const int*)d_in[4];
    float* out    = (float*)d_out;
    float* nll_ws = (float*)d_ws;  // 512 floats

    cbert_logits_kernel<<<BB, 1024, 0, stream>>>(
        reps, weight, bias, sense_ids, target_ids, out, nll_ws);
    cbert_loss_kernel<<<1, 64, 0, stream>>>(nll_ws, out);
}